// Round 3
// baseline (479.785 us; speedup 1.0000x reference)
//
#include <hip/hip_runtime.h>
#include <cmath>

// Forbid FMA contraction: the reference check is a float32 numpy replay with
// individually-rounded ops. We opt into FMA explicitly (fmaf) only where
// BLAS sgemm itself uses an FMA chain.
#pragma clang fp contract(off)

#define NLV 16
#define TSZ (1u << 19)
#define TMASK (TSZ - 1u)
#define PR1 2654435761u
#define PR2 805459861u

struct ResT { float r[NLV]; };

__global__ __launch_bounds__(256) void ngp_fused(
    const float* __restrict__ g_pos,
    const float* __restrict__ g_rx,
    const float* __restrict__ g_tab,
    const float* __restrict__ g_W1,
    const float* __restrict__ g_W2,
    const float* __restrict__ g_aabb,
    const int*   __restrict__ g_deg,
    float* __restrict__ g_out,
    int N, ResT rt)
{
    int n = blockIdx.x * 256 + threadIdx.x;
    if (n >= N) return;

    // ---- AABB normalize, pure fp32 single ops (bit-exact vs np fp32) ----
    float a0 = g_aabb[0], a1 = g_aabb[1], a2 = g_aabb[2];
    float s0 = fmaxf(g_aabb[3] - a0, 1e-6f);
    float s1 = fmaxf(g_aabb[4] - a1, 1e-6f);
    float s2 = fmaxf(g_aabb[5] - a2, 1e-6f);
    float posx = g_pos[3*n+0], posy = g_pos[3*n+1], posz = g_pos[3*n+2];
    float nx = (posx - a0) / s0;
    float ny = (posy - a1) / s1;
    float nz = (posz - a2) / s2;
    bool sel = (nx >= 0.f) && (nx <= 1.f) && (ny >= 0.f) && (ny <= 1.f)
            && (nz >= 0.f) && (nz <= 1.f);
    float pnx = fminf(fmaxf(nx, 0.f), 1.f);
    float pny = fminf(fmaxf(ny, 0.f), 1.f);
    float pnz = fminf(fmaxf(nz, 0.f), 1.f);

    // ---- pass 1: hash encode (fp32, np-faithful rounding), z1 = feats@W1 ----
    // z1 accumulated as BLAS-sgemm-style single FMA chain, ascending k.
    float z1[32];
#pragma unroll
    for (int i = 0; i < 32; ++i) z1[i] = 0.f;

    for (int l = 0; l < NLV; ++l) {
        float res = rt.r[l];
        float fx = pnx * res, fy = pny * res, fz = pnz * res;
        float x0 = floorf(fx), y0 = floorf(fy), z0 = floorf(fz);
        float wx = fx - x0, wy = fy - y0, wz = fz - z0;
        float omx = 1.f - wx, omy = 1.f - wy, omz = 1.f - wz;
        unsigned ux = (unsigned)x0, uy = (unsigned)y0, uz = (unsigned)z0;
        unsigned hx0 = ux,        hx1 = ux + 1u;
        unsigned hy0 = uy * PR1,  hy1 = (uy + 1u) * PR1;
        unsigned hz0 = uz * PR2,  hz1 = (uz + 1u) * PR2;
        const float2* tl = (const float2*)g_tab + (size_t)l * TSZ;
        float f0 = 0.f, f1 = 0.f;
#pragma unroll
        for (int c = 0; c < 8; ++c) {
            unsigned hh = ((c & 4) ? hx1 : hx0) ^ ((c & 2) ? hy1 : hy0) ^ ((c & 1) ? hz1 : hz0);
            float2 fv = tl[hh & TMASK];
            // wc = ((x)*(y))*(z), each op individually rounded (np prod order)
            float wgt = ((c & 4) ? wx : omx) * ((c & 2) ? wy : omy);
            wgt = wgt * ((c & 1) ? wz : omz);
            // (f*wc).sum(1): rounded product, then sequential add c=0..7
            float t0 = fv.x * wgt;
            float t1 = fv.y * wgt;
            f0 = f0 + t0;
            f1 = f1 + t1;
        }
        const float* w1a = g_W1 + (2 * l) * 32;      // row k=2l
        const float* w1b = g_W1 + (2 * l + 1) * 32;  // row k=2l+1
#pragma unroll
        for (int i = 0; i < 32; ++i) {
            float acc = fmaf(f0, w1a[i], z1[i]);     // k=2l first (ascending)
            z1[i] = fmaf(f1, w1b[i], acc);           // then k=2l+1
        }
    }

    // ---- relu + second layer (sgemm FMA chain, ascending j) ----
    unsigned mask = 0u;
    float sh[32];
#pragma unroll
    for (int o = 0; o < 32; ++o) sh[o] = 0.f;
#pragma unroll
    for (int i = 0; i < 32; ++i) {
        bool on = (z1[i] > 0.f);
        if (on) mask |= (1u << i);
        float h = on ? z1[i] : 0.f;
        const float* w2r = g_W2 + i * 32;
#pragma unroll
        for (int o = 0; o < 32; ++o) sh[o] = fmaf(h, w2r[o], sh[o]);
    }

    const float C0c = 0.28209479177387814f;
    float d0 = C0c * sh[0], d1 = C0c * sh[1];

    // ---- view dirs + SH basis + scat (smooth; magnitudes ~1e-3) ----
    float rx0 = g_rx[0], rx1 = g_rx[1], rx2 = g_rx[2];
    float dxw = rx0 - posx, dyw = rx1 - posy, dzw = rx2 - posz;
    float dnorm = sqrtf(dxw*dxw + dyw*dyw + dzw*dzw);
    float dinv = 1.f / fmaxf(dnorm, 1e-20f);
    float X = dxw * dinv, Yd = dyw * dinv, Z = dzw * dinv;
    float xx = X*X, yy = Yd*Yd, zz = Z*Z;
    float xy = X*Yd, yz = Yd*Z, xz = X*Z;
    float Yb[16];
    Yb[0]  = 0.28209479177387814f;
    Yb[1]  = -0.4886025119029199f * Yd;
    Yb[2]  =  0.4886025119029199f * Z;
    Yb[3]  = -0.4886025119029199f * X;
    Yb[4]  =  1.0925484305920792f * xy;
    Yb[5]  = -1.0925484305920792f * yz;
    Yb[6]  =  0.31539156525252005f * (2.f*zz - xx - yy);
    Yb[7]  = -1.0925484305920792f * xz;
    Yb[8]  =  0.5462742152960396f * (xx - yy);
    Yb[9]  = -0.5900435899266435f * Yd * (3.f*xx - yy);
    Yb[10] =  2.890611442640554f  * xy * Z;
    Yb[11] = -0.4570457994644658f * Yd * (4.f*zz - xx - yy);
    Yb[12] =  0.3731763325901154f * Z * (2.f*zz - 3.f*xx - 3.f*yy);
    Yb[13] = -0.4570457994644658f * X * (4.f*zz - xx - yy);
    Yb[14] =  1.445305721320277f  * Z * (xx - yy);
    Yb[15] = -0.5900435899266435f * X * (xx - 3.f*yy);

    int deg = g_deg[0];
    int nact = (deg + 1) * (deg + 1);
    float sc0 = 0.f, sc1 = 0.f;
#pragma unroll
    for (int c = 0; c < 16; ++c) {
        float yc = (c < nact) ? Yb[c] : 0.f;
        sc0 = fmaf(yc, sh[2*c+0], sc0);
        sc1 = fmaf(yc, sh[2*c+1], sc1);
    }

    float* op = g_out + (size_t)n * 39;
    op[0] = sel ? d0  : 0.f;
    op[1] = sel ? d1  : 0.f;
    op[2] = sel ? sc0 : 0.f;
    op[3] = sel ? sc1 : 0.f;
#pragma unroll
    for (int c = 0; c < 32; ++c) op[7 + c] = sel ? sh[c] : 0.f;

    // ---- backward head: q = dloss/dsh[0..1] = C0*d/|d| ----
    float ss = d0*d0 + d1*d1;
    float q0 = 0.f, q1 = 0.f;
    if (ss > 0.f) {
        float sr = sqrtf(ss);
        q0 = C0c * d0 / sr;
        q1 = C0c * d1 / sr;
    }
    float dzv[32];
#pragma unroll
    for (int i = 0; i < 32; ++i) {
        float dh = fmaf(q0, g_W2[i*32+0], q1 * g_W2[i*32+1]);
        dzv[i] = ((mask >> i) & 1u) ? dh : 0.f;
    }

    // ---- pass 2: gradient of trilinear interp wrt pn (smooth; fp32 fast) ----
    float gx = 0.f, gy = 0.f, gz = 0.f;
    for (int l = 0; l < NLV; ++l) {
        const float* w1a = g_W1 + (2 * l) * 32;
        const float* w1b = g_W1 + (2 * l + 1) * 32;
        float da = 0.f, db = 0.f;
#pragma unroll
        for (int i = 0; i < 32; ++i) {
            da = fmaf(w1a[i], dzv[i], da);
            db = fmaf(w1b[i], dzv[i], db);
        }
        float res = rt.r[l];
        // identical fp32 cell/weight computation as pass 1 (bit-same)
        float fx = pnx * res, fy = pny * res, fz = pnz * res;
        float x0 = floorf(fx), y0 = floorf(fy), z0 = floorf(fz);
        float wx = fx - x0, wy = fy - y0, wz = fz - z0;
        float omx = 1.f - wx, omy = 1.f - wy, omz = 1.f - wz;
        unsigned ux = (unsigned)x0, uy = (unsigned)y0, uz = (unsigned)z0;
        unsigned hx0 = ux,        hx1 = ux + 1u;
        unsigned hy0 = uy * PR1,  hy1 = (uy + 1u) * PR1;
        unsigned hz0 = uz * PR2,  hz1 = (uz + 1u) * PR2;
        const float2* tl = (const float2*)g_tab + (size_t)l * TSZ;
        float lx = 0.f, ly = 0.f, lz = 0.f;
#pragma unroll
        for (int c = 0; c < 8; ++c) {
            unsigned hh = ((c & 4) ? hx1 : hx0) ^ ((c & 2) ? hy1 : hy0) ^ ((c & 1) ? hz1 : hz0);
            float2 fv = tl[hh & TMASK];
            float common = fmaf(da, fv.x, db * fv.y);
            float wxv = (c & 4) ? wx : omx;
            float wyv = (c & 2) ? wy : omy;
            float wzv = (c & 1) ? wz : omz;
            float cs = common;
            float tx = ((c & 4) ? cs : -cs) * (wyv * wzv);
            float ty = ((c & 2) ? cs : -cs) * (wxv * wzv);
            float tz = ((c & 1) ? cs : -cs) * (wxv * wyv);
            lx = lx + tx; ly = ly + ty; lz = lz + tz;
        }
        gx = fmaf(res, lx, gx);
        gy = fmaf(res, ly, gy);
        gz = fmaf(res, lz, gz);
    }

    // ---- world-space normal ----
    float gwx = gx / s0, gwy = gy / s1, gwz = gz / s2;
    float gn = sqrtf(gwx*gwx + gwy*gwy + gwz*gwz);
    float ginv = -1.f / fmaxf(gn, 1e-20f);
    op[4] = sel ? gwx * ginv : 0.f;
    op[5] = sel ? gwy * ginv : 0.f;
    op[6] = sel ? gwz * ginv : 0.f;
}

extern "C" void kernel_launch(void* const* d_in, const int* in_sizes, int n_in,
                              void* d_out, int out_size, void* d_ws, size_t ws_size,
                              hipStream_t stream)
{
    const float* g_pos  = (const float*)d_in[0];
    const float* g_rx   = (const float*)d_in[1];
    const float* g_tab  = (const float*)d_in[2];
    const float* g_W1   = (const float*)d_in[3];
    const float* g_W2   = (const float*)d_in[4];
    const float* g_aabb = (const float*)d_in[5];
    const int*   g_deg  = (const int*)d_in[6];
    float* g_out = (float*)d_out;

    int N = in_sizes[0] / 3;

    // RES exactly as the reference: python float64 exp/log/pow, cast to fp32.
    ResT rt;
    double scale = exp((log(4096.0) - log(16.0)) / 15.0);
    for (int l = 0; l < NLV; ++l) rt.r[l] = (float)(16.0 * pow(scale, (double)l));

    int blocks = (N + 255) / 256;
    ngp_fused<<<blocks, 256, 0, stream>>>(g_pos, g_rx, g_tab, g_W1, g_W2,
                                          g_aabb, g_deg, g_out, N, rt);
}